// Round 1
// baseline (899.426 us; speedup 1.0000x reference)
//
#include <hip/hip_runtime.h>
#include <math.h>

#define F_IN 256
#define F_OUT 64
#define NEG_SLOPE 0.2f

// ---------------------------------------------------------------------------
// Fused GEMM: h = x @ W  [N,64], a_src = h @ att_src, a_dst = h @ att_dst.
// Block = 256 threads = 4 waves; each wave computes 8 rows x 64 cols.
// LDS: W k-chunk [64][64] (16KB) + x tile [32][64] (8KB).
// ---------------------------------------------------------------------------
__global__ __launch_bounds__(256) void gemm_kernel(
    const float* __restrict__ x, const float* __restrict__ W,
    const float* __restrict__ att_src, const float* __restrict__ att_dst,
    float* __restrict__ h, float* __restrict__ a_src, float* __restrict__ a_dst,
    int N)
{
    __shared__ float sW[64][64];   // [kk][col]
    __shared__ float sX[32][64];   // [local row][kk]
    const int t = threadIdx.x;
    const int lane = t & 63;
    const int w = t >> 6;
    const int rowBase = blockIdx.x * 32;

    float acc[8];
#pragma unroll
    for (int r = 0; r < 8; r++) acc[r] = 0.f;

    for (int kc = 0; kc < F_IN / 64; kc++) {
        // load W chunk: 64x64 = 1024 float4, 4 per thread
#pragma unroll
        for (int it = 0; it < 4; it++) {
            int q = t + it * 256;
            int kk = q >> 4;
            int c4 = (q & 15) << 2;
            *((float4*)&sW[kk][c4]) = *(const float4*)&W[(kc * 64 + kk) * 64 + c4];
        }
        // load x tile: 32x64 = 512 float4, 2 per thread
#pragma unroll
        for (int it = 0; it < 2; it++) {
            int q = t + it * 256;
            int r = q >> 4;
            int c4 = (q & 15) << 2;
            int row = rowBase + r;
            float4 v = make_float4(0.f, 0.f, 0.f, 0.f);
            if (row < N) v = *(const float4*)&x[(size_t)row * F_IN + kc * 64 + c4];
            *((float4*)&sX[r][c4]) = v;
        }
        __syncthreads();
#pragma unroll 8
        for (int kk = 0; kk < 64; kk++) {
            float wv = sW[kk][lane];
#pragma unroll
            for (int r = 0; r < 8; r++)
                acc[r] = fmaf(sX[w * 8 + r][kk], wv, acc[r]);
        }
        __syncthreads();
    }

    const float as = att_src[lane];
    const float ad = att_dst[lane];
#pragma unroll
    for (int r = 0; r < 8; r++) {
        int row = rowBase + w * 8 + r;
        if (row < N) {
            h[(size_t)row * 64 + lane] = acc[r];
            float s1 = acc[r] * as;
            float s2 = acc[r] * ad;
#pragma unroll
            for (int o = 32; o > 0; o >>= 1) {
                s1 += __shfl_xor(s1, o, 64);
                s2 += __shfl_xor(s2, o, 64);
            }
            if (lane == 0) { a_src[row] = s1; a_dst[row] = s2; }
        }
    }
}

// ---------------------------------------------------------------------------
// CSR build: histogram of dst, 2-level exclusive scan, scatter (col + logit).
// ---------------------------------------------------------------------------
__global__ void hist_kernel(const int* __restrict__ dst, int* __restrict__ deg, int E)
{
    int e = blockIdx.x * blockDim.x + threadIdx.x;
    if (e < E) atomicAdd(&deg[dst[e]], 1);
}

__global__ __launch_bounds__(256) void scan1_kernel(
    const int* __restrict__ deg, int* __restrict__ row_tmp,
    int* __restrict__ bsum, int N)
{
    __shared__ int s[256];
    int t = threadIdx.x;
    int idx = blockIdx.x * 256 + t;
    int d = (idx < N) ? deg[idx] : 0;
    s[t] = d;
    __syncthreads();
    for (int off = 1; off < 256; off <<= 1) {
        int v = (t >= off) ? s[t - off] : 0;
        __syncthreads();
        s[t] += v;
        __syncthreads();
    }
    if (idx < N) row_tmp[idx] = s[t] - d;   // exclusive
    if (t == 255) bsum[blockIdx.x] = s[255];
}

__global__ void scan2_kernel(int* bsum, int NB)
{
    if (threadIdx.x == 0 && blockIdx.x == 0) {
        int run = 0;
        for (int b = 0; b < NB; b++) { int v = bsum[b]; bsum[b] = run; run += v; }
    }
}

__global__ __launch_bounds__(256) void scan3_kernel(
    const int* __restrict__ row_tmp, const int* __restrict__ bsum,
    int* __restrict__ row_ptr, int* __restrict__ cursor, int N, int E)
{
    int idx = blockIdx.x * 256 + threadIdx.x;
    if (idx < N) {
        int rp = row_tmp[idx] + bsum[blockIdx.x];
        row_ptr[idx] = rp;
        cursor[idx] = rp;
    }
    if (idx == 0) row_ptr[N] = E;
}

__global__ void scatter_kernel(
    const int* __restrict__ ei, const float* __restrict__ a_src,
    const float* __restrict__ a_dst, int* __restrict__ cursor,
    int* __restrict__ col, float* __restrict__ val, int E)
{
    int e = blockIdx.x * blockDim.x + threadIdx.x;
    if (e >= E) return;
    int j = ei[e];        // src (message sender)
    int i = ei[E + e];    // dst (message target)
    float v = a_src[j] + a_dst[i];
    v = (v > 0.f) ? v : NEG_SLOPE * v;           // LeakyReLU(0.2)
    int pos = atomicAdd(&cursor[i], 1);
    col[pos] = j;
    val[pos] = v;
}

// ---------------------------------------------------------------------------
// Node aggregation: one wave per node, lane = output feature.
// Softmax over in-edges (+ self loop), out = (sum p*h) / (sum p + eps) + bias.
// ---------------------------------------------------------------------------
__global__ __launch_bounds__(256) void node_kernel(
    const float* __restrict__ h, const float* __restrict__ a_src,
    const float* __restrict__ a_dst, const int* __restrict__ row_ptr,
    const int* __restrict__ col, const float* __restrict__ val,
    const float* __restrict__ bias, float* __restrict__ out, int N)
{
    int w = threadIdx.x >> 6;
    int lane = threadIdx.x & 63;
    int i = blockIdx.x * 4 + w;
    if (i >= N) return;

    int start = row_ptr[i];
    int end = row_ptr[i + 1];

    float vself = a_src[i] + a_dst[i];
    vself = (vself > 0.f) ? vself : NEG_SLOPE * vself;

    // pass 1: max logit (self loop included as init)
    float m = vself;
    for (int e = start + lane; e < end; e += 64) m = fmaxf(m, val[e]);
#pragma unroll
    for (int o = 32; o > 0; o >>= 1) m = fmaxf(m, __shfl_xor(m, o, 64));

    // pass 2: accumulate
    float den = 0.f, acc = 0.f;
    for (int e = start; e < end; e++) {
        int j = col[e];
        float p = __expf(val[e] - m);
        den += p;
        acc = fmaf(p, h[(size_t)j * 64 + lane], acc);
    }
    float pself = __expf(vself - m);
    den += pself;
    acc = fmaf(pself, h[(size_t)i * 64 + lane], acc);

    out[(size_t)i * 64 + lane] = acc / (den + 1e-16f) + bias[lane];
}

// ---------------------------------------------------------------------------
extern "C" void kernel_launch(void* const* d_in, const int* in_sizes, int n_in,
                              void* d_out, int out_size, void* d_ws, size_t ws_size,
                              hipStream_t stream)
{
    const float* x      = (const float*)d_in[0];
    const int*   ei     = (const int*)d_in[1];
    const float* W      = (const float*)d_in[2];
    const float* att_sr = (const float*)d_in[3];
    const float* att_ds = (const float*)d_in[4];
    const float* bias   = (const float*)d_in[5];
    float* out = (float*)d_out;

    const int N  = in_sizes[0] / F_IN;
    const int E  = in_sizes[1] / 2;
    const int NB = (N + 255) / 256;

    char* ws = (char*)d_ws;
    size_t off = 0;
    auto alloc = [&](size_t bytes) -> void* {
        void* p = ws + off;
        off = (off + bytes + 255) & ~(size_t)255;
        return p;
    };
    float* h       = (float*)alloc((size_t)N * 64 * 4);
    float* a_src   = (float*)alloc((size_t)N * 4);
    float* a_dst   = (float*)alloc((size_t)N * 4);
    int*   deg     = (int*)alloc((size_t)N * 4);
    int*   row_tmp = (int*)alloc((size_t)N * 4);
    int*   bsum    = (int*)alloc((size_t)NB * 4);
    int*   row_ptr = (int*)alloc((size_t)(N + 1) * 4);
    int*   cursor  = (int*)alloc((size_t)N * 4);
    int*   col     = (int*)alloc((size_t)E * 4);
    float* val     = (float*)alloc((size_t)E * 4);
    (void)ws_size; (void)n_in; (void)out_size;

    hipMemsetAsync(deg, 0, (size_t)N * 4, stream);

    gemm_kernel<<<(N + 31) / 32, 256, 0, stream>>>(x, W, att_sr, att_ds, h, a_src, a_dst, N);
    hist_kernel<<<(E + 255) / 256, 256, 0, stream>>>(ei + E, deg, E);
    scan1_kernel<<<NB, 256, 0, stream>>>(deg, row_tmp, bsum, N);
    scan2_kernel<<<1, 64, 0, stream>>>(bsum, NB);
    scan3_kernel<<<NB, 256, 0, stream>>>(row_tmp, bsum, row_ptr, cursor, N, E);
    scatter_kernel<<<(E + 255) / 256, 256, 0, stream>>>(ei, a_src, a_dst, cursor, col, val, E);
    node_kernel<<<(N + 3) / 4, 256, 0, stream>>>(h, a_src, a_dst, row_ptr, col, val, bias, out, N);
}

// Round 2
// 615.304 us; speedup vs baseline: 1.4618x; 1.4618x over previous
//
#include <hip/hip_runtime.h>
#include <hip/hip_bf16.h>
#include <math.h>

#define F_IN 256
#define F_OUT 64
#define NEG_SLOPE 0.2f

// ---------------------------------------------------------------------------
// GEMM: h16 = bf16(x @ W), a_src = h@att_src, a_dst = h@att_dst (fp32).
// lane = row (64 rows/block), wave w owns cols w*16..w*16+15 (16 fp32 acc).
// x staged transposed in LDS sX[k][row] with +1 pad -> conflict-free reads.
// W read via wave-uniform scalar loads (s_load) -> no vector-mem/LDS cost.
// ---------------------------------------------------------------------------
__global__ __launch_bounds__(256) void gemm_kernel(
    const float* __restrict__ x, const float* __restrict__ W,
    const float* __restrict__ att_src, const float* __restrict__ att_dst,
    __hip_bfloat16* __restrict__ h16, float* __restrict__ a_src,
    float* __restrict__ a_dst, int N)
{
    __shared__ float sX[64][65];      // [k within chunk][row], padded
    __shared__ float sPa[4][64];
    __shared__ float sPd[4][64];

    const int t = threadIdx.x;
    const int lane = t & 63;
    const int w = t >> 6;
    const int rowBase = blockIdx.x * 64;
    const int row = rowBase + lane;
    const int c0 = __builtin_amdgcn_readfirstlane(w * 16);  // uniform col base

    float acc[16];
#pragma unroll
    for (int c = 0; c < 16; c++) acc[c] = 0.f;

    const int kq = t & 15;   // k quarter: float4 at k = kq*4
    const int rr = t >> 4;   // row sub-index 0..15

    for (int kc = 0; kc < F_IN / 64; kc++) {
        // stage x[rowBase..+63][kc*64..+63] transposed into sX
#pragma unroll
        for (int p = 0; p < 4; p++) {
            int r = rr + p * 16;
            float4 v = make_float4(0.f, 0.f, 0.f, 0.f);
            if (rowBase + r < N)
                v = *(const float4*)&x[(size_t)(rowBase + r) * F_IN + kc * 64 + kq * 4];
            sX[kq * 4 + 0][r] = v.x;
            sX[kq * 4 + 1][r] = v.y;
            sX[kq * 4 + 2][r] = v.z;
            sX[kq * 4 + 3][r] = v.w;
        }
        __syncthreads();

        const float* Wc = W + (size_t)(kc * 64) * F_OUT + c0;
#pragma unroll 4
        for (int kk = 0; kk < 64; kk++) {
            float xv = sX[kk][lane];
            const float* wr = Wc + (size_t)kk * F_OUT;   // uniform address
#pragma unroll
            for (int c = 0; c < 16; c++)
                acc[c] = fmaf(xv, wr[c], acc[c]);
        }
        __syncthreads();
    }

    // attention partials (cols split across waves -> LDS reduce)
    float asp = 0.f, adp = 0.f;
#pragma unroll
    for (int c = 0; c < 16; c++) {
        asp = fmaf(acc[c], att_src[c0 + c], asp);
        adp = fmaf(acc[c], att_dst[c0 + c], adp);
    }
    sPa[w][lane] = asp;
    sPd[w][lane] = adp;

    // h write: 16 contiguous bf16 per lane = 32 B (two 16-B stores)
    if (row < N) {
        __hip_bfloat16 tmp[16];
#pragma unroll
        for (int c = 0; c < 16; c++) tmp[c] = __float2bfloat16(acc[c]);
        int4* dst = (int4*)(h16 + (size_t)row * F_OUT + c0);
        dst[0] = ((int4*)tmp)[0];
        dst[1] = ((int4*)tmp)[1];
    }

    __syncthreads();
    if (w == 0 && row < N) {
        a_src[row] = sPa[0][lane] + sPa[1][lane] + sPa[2][lane] + sPa[3][lane];
        a_dst[row] = sPd[0][lane] + sPd[1][lane] + sPd[2][lane] + sPd[3][lane];
    }
}

// ---------------------------------------------------------------------------
// CSR build
// ---------------------------------------------------------------------------
__global__ void hist_kernel(const int* __restrict__ dst, int* __restrict__ deg, int E)
{
    int idx = blockIdx.x * blockDim.x + threadIdx.x;
    int e4 = idx * 4;
    if (e4 + 3 < E) {
        int4 d = *(const int4*)&dst[e4];
        atomicAdd(&deg[d.x], 1);
        atomicAdd(&deg[d.y], 1);
        atomicAdd(&deg[d.z], 1);
        atomicAdd(&deg[d.w], 1);
    } else {
        for (int e = e4; e < E; e++) atomicAdd(&deg[dst[e]], 1);
    }
}

__global__ __launch_bounds__(256) void scan1_kernel(
    const int* __restrict__ deg, int* __restrict__ row_tmp,
    int* __restrict__ bsum, int N)
{
    __shared__ int s[256];
    int t = threadIdx.x;
    int idx = blockIdx.x * 256 + t;
    int d = (idx < N) ? deg[idx] : 0;
    s[t] = d;
    __syncthreads();
    for (int off = 1; off < 256; off <<= 1) {
        int v = (t >= off) ? s[t - off] : 0;
        __syncthreads();
        s[t] += v;
        __syncthreads();
    }
    if (idx < N) row_tmp[idx] = s[t] - d;   // exclusive
    if (t == 255) bsum[blockIdx.x] = s[255];
}

__global__ __launch_bounds__(512) void scan2_kernel(int* bsum, int NB)
{
    __shared__ int s[512];
    int t = threadIdx.x;
    if (NB <= 512) {
        int v = (t < NB) ? bsum[t] : 0;
        s[t] = v;
        __syncthreads();
        for (int off = 1; off < 512; off <<= 1) {
            int u = (t >= off) ? s[t - off] : 0;
            __syncthreads();
            s[t] += u;
            __syncthreads();
        }
        if (t < NB) bsum[t] = s[t] - v;     // exclusive
    } else if (t == 0 && blockIdx.x == 0) {
        int run = 0;
        for (int b = 0; b < NB; b++) { int v = bsum[b]; bsum[b] = run; run += v; }
    }
}

__global__ __launch_bounds__(256) void scan3_kernel(
    const int* __restrict__ row_tmp, const int* __restrict__ bsum,
    int* __restrict__ row_ptr, int* __restrict__ cursor, int N, int E)
{
    int idx = blockIdx.x * 256 + threadIdx.x;
    if (idx < N) {
        int rp = row_tmp[idx] + bsum[blockIdx.x];
        row_ptr[idx] = rp;
        cursor[idx] = rp;
    }
    if (idx == 0) row_ptr[N] = E;
}

// scatter: one packed 8-B write per edge {src, exp(leakyrelu(logit))}
__global__ void scatter_kernel(
    const int* __restrict__ ei, const float* __restrict__ a_src,
    const float* __restrict__ a_dst, int* __restrict__ cursor,
    int2* __restrict__ meta, int E)
{
    int e = blockIdx.x * blockDim.x + threadIdx.x;
    if (e >= E) return;
    int j = ei[e];        // src (message sender)
    int i = ei[E + e];    // dst (message target)
    float v = a_src[j] + a_dst[i];
    v = (v > 0.f) ? v : NEG_SLOPE * v;           // LeakyReLU(0.2)
    float p = __expf(v);                          // |v| <= ~10: no max needed
    int pos = atomicAdd(&cursor[i], 1);
    meta[pos] = make_int2(j, __float_as_int(p));
}

// ---------------------------------------------------------------------------
// Node aggregation: one wave/node, lane=feature, unroll 8 for MLP.
// ---------------------------------------------------------------------------
__global__ __launch_bounds__(256) void node_kernel(
    const __hip_bfloat16* __restrict__ h16, const float* __restrict__ a_src,
    const float* __restrict__ a_dst, const int* __restrict__ row_ptr,
    const int2* __restrict__ meta, const float* __restrict__ bias,
    float* __restrict__ out, int N)
{
    int w = threadIdx.x >> 6;
    int lane = threadIdx.x & 63;
    int i = blockIdx.x * 4 + w;
    if (i >= N) return;

    int s = row_ptr[i];
    int e = row_ptr[i + 1];

    float vs = a_src[i] + a_dst[i];
    vs = (vs > 0.f) ? vs : NEG_SLOPE * vs;
    float pself = __expf(vs);
    float den = pself;
    float acc = pself * __bfloat162float(h16[(size_t)i * F_OUT + lane]);

    int k = s;
    for (; k + 8 <= e; k += 8) {
        int2 m[8];
#pragma unroll
        for (int u = 0; u < 8; u++) m[u] = meta[k + u];
        float g[8];
#pragma unroll
        for (int u = 0; u < 8; u++)
            g[u] = __bfloat162float(h16[(size_t)m[u].x * F_OUT + lane]);
#pragma unroll
        for (int u = 0; u < 8; u++) {
            float p = __int_as_float(m[u].y);
            den += p;
            acc = fmaf(p, g[u], acc);
        }
    }
    for (; k < e; k++) {
        int2 m = meta[k];
        float p = __int_as_float(m.y);
        den += p;
        acc = fmaf(p, __bfloat162float(h16[(size_t)m.x * F_OUT + lane]), acc);
    }

    out[(size_t)i * F_OUT + lane] = acc / (den + 1e-16f) + bias[lane];
}

// ---------------------------------------------------------------------------
extern "C" void kernel_launch(void* const* d_in, const int* in_sizes, int n_in,
                              void* d_out, int out_size, void* d_ws, size_t ws_size,
                              hipStream_t stream)
{
    const float* x      = (const float*)d_in[0];
    const int*   ei     = (const int*)d_in[1];
    const float* W      = (const float*)d_in[2];
    const float* att_sr = (const float*)d_in[3];
    const float* att_ds = (const float*)d_in[4];
    const float* bias   = (const float*)d_in[5];
    float* out = (float*)d_out;

    const int N  = in_sizes[0] / F_IN;
    const int E  = in_sizes[1] / 2;
    const int NB = (N + 255) / 256;

    char* ws = (char*)d_ws;
    size_t off = 0;
    auto alloc = [&](size_t bytes) -> void* {
        void* p = ws + off;
        off = (off + bytes + 255) & ~(size_t)255;
        return p;
    };
    __hip_bfloat16* h16 = (__hip_bfloat16*)alloc((size_t)N * F_OUT * 2);
    float* a_src   = (float*)alloc((size_t)N * 4);
    float* a_dst   = (float*)alloc((size_t)N * 4);
    int*   deg     = (int*)alloc((size_t)N * 4);
    int*   row_tmp = (int*)alloc((size_t)N * 4);
    int*   bsum    = (int*)alloc((size_t)NB * 4);
    int*   row_ptr = (int*)alloc((size_t)(N + 1) * 4);
    int*   cursor  = (int*)alloc((size_t)N * 4);
    int2*  meta    = (int2*)alloc((size_t)E * 8);
    (void)ws_size; (void)n_in; (void)out_size;

    hipMemsetAsync(deg, 0, (size_t)N * 4, stream);

    gemm_kernel<<<(N + 63) / 64, 256, 0, stream>>>(x, W, att_sr, att_ds, h16, a_src, a_dst, N);
    hist_kernel<<<(E / 4 + 255) / 256, 256, 0, stream>>>(ei + E, deg, E);
    scan1_kernel<<<NB, 256, 0, stream>>>(deg, row_tmp, bsum, N);
    scan2_kernel<<<1, 512, 0, stream>>>(bsum, NB);
    scan3_kernel<<<NB, 256, 0, stream>>>(row_tmp, bsum, row_ptr, cursor, N, E);
    scatter_kernel<<<(E + 255) / 256, 256, 0, stream>>>(ei, a_src, a_dst, cursor, meta, E);
    node_kernel<<<(N + 3) / 4, 256, 0, stream>>>(h16, a_src, a_dst, row_ptr, meta, bias, out, N);
}